// Round 11
// baseline (56.243 us; speedup 1.0000x reference)
//
#include <hip/hip_runtime.h>
#include <math.h>

#define BB   4
#define NN   4096
#define DD   128
#define NCLS 5
#define SS   800      // (N - NQ) / NCLS
#define KK   400      // int(0.5 * S)
#define NQ   96
#define MM   (NCLS*KK + NQ)   // 2096
#define NSUP (NCLS*SS)        // 4000

typedef float f4 __attribute__((ext_vector_type(4)));
typedef int   i4 __attribute__((ext_vector_type(4)));

// ---------------- scores: f64 dot, exact f32 sigmoid (R2/R3-verified, verbatim) ----------------
__global__ void score_kernel(const float* __restrict__ X, const float* __restrict__ W,
                             const float* __restrict__ bias,
                             float* __restrict__ scoreF) {
    int row  = blockIdx.x * 4 + (threadIdx.x >> 6);   // 4 waves / block
    int lane = threadIdx.x & 63;
    if (row >= BB * NN) return;
    const float* x = X + (size_t)row * DD;
    double acc = (double)x[lane]      * (double)W[lane]
               + (double)x[lane + 64] * (double)W[lane + 64];
    #pragma unroll
    for (int off = 32; off > 0; off >>= 1) acc += __shfl_down(acc, off);
    if (lane == 0) {
        float z32 = (float)acc;
        float u   = (z32 + bias[0]) / 100.0f;
        float e   = (float)exp(-(double)u);
        float t   = 1.0f + e;
        float s   = 1.0f / t;
        scoreF[row] = s;
    }
}

// ---------------- top-400 per (b,class): register bitonic (R3-verified, verbatim) ----------------
__global__ void __launch_bounds__(1024)
topk_kernel(const float* __restrict__ scoreF, int* __restrict__ gidx, float* __restrict__ gvals) {
    __shared__ unsigned long long buf[2][1024];
    const int b = blockIdx.x / NCLS;
    const int c = blockIdx.x % NCLS;
    const int t = threadIdx.x;

    if (c == 0 && t >= 512 && t < 512 + NQ) {
        int q  = t - 512;
        int gi = NSUP + q;
        int m  = NCLS * KK + q;
        gidx [b * MM + m] = gi;
        gvals[b * MM + m] = scoreF[(size_t)b * NN + gi];
    }

    const float* sc = scoreF + (size_t)b * NN + c * SS;
    unsigned long long v = 0ull;    // pad sinks
    if (t < SS)
        v = ((unsigned long long)__float_as_uint(sc[t]) << 32) | (unsigned int)(1023 - t);

    int p = 0;
    for (int k = 2; k <= 1024; k <<= 1) {
        for (int j = k >> 1; j > 0; j >>= 1) {
            unsigned long long o;
            if (j >= 64) {
                buf[p][t] = v;
                __syncthreads();
                o = buf[p][t ^ j];
                p ^= 1;   // next reuse of this buffer is 2 stages (1 barrier) away
            } else {
                unsigned int lo = __shfl_xor((unsigned int)(v & 0xFFFFFFFFu), j);
                unsigned int hi = __shfl_xor((unsigned int)(v >> 32), j);
                o = ((unsigned long long)hi << 32) | lo;
            }
            bool keepMax = (((t & k) == 0) == ((t & j) == 0));
            v = keepMax ? (v > o ? v : o) : (v < o ? v : o);
        }
    }

    if (t < KK) {
        int li = 1023 - (int)(v & 0xFFFFFFFFull);
        gidx [b * MM + c * KK + t] = c * SS + li;
        gvals[b * MM + c * KK + t] = __uint_as_float((unsigned int)(v >> 32));
    }
}

// ---------------- fused new_A + new_X + idx: 2 rows/block, shared index loads ----------------
// Change vs R10-verified newxa: each 512-thread block handles TWO output rows of the
// same batch. The two rows share identical column indices -> one i4 index load feeds
// both gathers; grid 8384->4192 (half the dispatch ramp); LDS 2x16KB, 4 blocks/CU
// (wave-capped 32 waves, same 8 staged rows/CU). HBM bytes unchanged.
__global__ void __launch_bounds__(512, 4)
newxa_kernel(const float* __restrict__ A, const float* __restrict__ X,
             const int* __restrict__ gidx, const float* __restrict__ gvals,
             float* __restrict__ outA, float* __restrict__ outX, float* __restrict__ outIdx) {
    __shared__ float rowA[2][NN];
    const int blk = blockIdx.x;               // b*(MM/2) + r2
    const int b   = blk / (MM / 2);
    const int r2  = blk % (MM / 2);
    const int bm0 = b * MM + 2 * r2;
    const int ri0 = gidx[bm0];
    const int ri1 = gidx[bm0 + 1];

    // async stage: waves 0-3 stage row0, waves 4-7 row1; 4 x global_load_lds_dwordx4
    // per wave, wave-uniform LDS base + lane*16 (linear dest), streaming HBM order.
    {
        const int wv = threadIdx.x >> 6, ln = threadIdx.x & 63;
        const int rsel = wv >> 2, wv2 = wv & 3;
        const float* arow = A + ((size_t)b * NN + (rsel ? ri1 : ri0)) * NN;
        #pragma unroll
        for (int sgm = 0; sgm < 4; ++sgm) {
            int base = (wv2 * 4 + sgm) * 256;              // float offset, wave-uniform
            const float* gsrc = arow + base + ln * 4;      // per-lane global addr
            float*       ldst = &rowA[rsel][base];         // wave-uniform LDS base
            __builtin_amdgcn_global_load_lds(
                (__attribute__((address_space(1))) void*)(const_cast<float*>(gsrc)),
                (__attribute__((address_space(3))) void*)(ldst),
                16, 0, 0);
        }
    }

    // newX + idx for both rows overlap the staging latency
    if (threadIdx.x < 2 * DD) {
        const int rs = threadIdx.x >> 7, d = threadIdx.x & (DD - 1);
        const int bm = bm0 + rs;
        const int ri = rs ? ri1 : ri0;
        float vscale = gvals[bm];
        outX[(size_t)bm * DD + d] = X[((size_t)b * NN + ri) * DD + d] * vscale;
        if (d == 0) outIdx[bm] = (float)ri;
    }
    __syncthreads();   // drains vmcnt (global_load_lds)

    // gather: one i4 index load (L2-hot) serves BOTH rows; coalesced f4 stores
    const int* gb = gidx + b * MM;            // 16B-aligned
    float* orow0 = outA + (size_t)bm0 * MM;
    float* orow1 = orow0 + MM;
    for (int jj = threadIdx.x * 4; jj < MM; jj += 2048) {
        i4 c4 = *(const i4*)(gb + jj);
        f4 v0, v1;
        v0.x = rowA[0][c4.x];  v1.x = rowA[1][c4.x];
        v0.y = rowA[0][c4.y];  v1.y = rowA[1][c4.y];
        v0.z = rowA[0][c4.z];  v1.z = rowA[1][c4.z];
        v0.w = rowA[0][c4.w];  v1.w = rowA[1][c4.w];
        *(f4*)(orow0 + jj) = v0;
        *(f4*)(orow1 + jj) = v1;
    }
}

extern "C" void kernel_launch(void* const* d_in, const int* in_sizes, int n_in,
                              void* d_out, int out_size, void* d_ws, size_t ws_size,
                              hipStream_t stream) {
    const float* A  = (const float*)d_in[0];
    const float* X  = (const float*)d_in[1];
    const float* W  = (const float*)d_in[2];
    const float* bi = (const float*)d_in[3];

    float* outA   = (float*)d_out;                         // B*M*M
    float* outX   = outA + (size_t)BB * MM * MM;           // B*M*D
    float* outIdx = outX + (size_t)BB * MM * DD;           // B*M

    char* ws = (char*)d_ws;
    float* scoreF = (float*)ws;                                 // B*N*4 = 65536
    int*   gidx   = (int*)  (ws + 65536);                       // B*M*4 = 33536
    float* gvals  = (float*)(ws + 65536 + 33536);               // B*M*4 = 33536

    score_kernel<<<(BB * NN) / 4, 256, 0, stream>>>(X, W, bi, scoreF);
    topk_kernel<<<BB * NCLS, 1024, 0, stream>>>(scoreF, gidx, gvals);
    newxa_kernel<<<(BB * MM) / 2, 512, 0, stream>>>(A, X, gidx, gvals, outA, outX, outIdx);
}

// Round 12
// 54.090 us; speedup vs baseline: 1.0398x; 1.0398x over previous
//
#include <hip/hip_runtime.h>
#include <math.h>

#define BB   4
#define NN   4096
#define DD   128
#define NCLS 5
#define SS   800      // (N - NQ) / NCLS
#define KK   400      // int(0.5 * S)
#define NQ   96
#define MM   (NCLS*KK + NQ)   // 2096
#define NSUP (NCLS*SS)        // 4000

typedef float f4 __attribute__((ext_vector_type(4)));
typedef int   i4 __attribute__((ext_vector_type(4)));

// ---------------- scores: f64 dot, exact f32 sigmoid (R2/R3-verified, verbatim) ----------------
__global__ void score_kernel(const float* __restrict__ X, const float* __restrict__ W,
                             const float* __restrict__ bias,
                             float* __restrict__ scoreF) {
    int row  = blockIdx.x * 4 + (threadIdx.x >> 6);   // 4 waves / block
    int lane = threadIdx.x & 63;
    if (row >= BB * NN) return;
    const float* x = X + (size_t)row * DD;
    double acc = (double)x[lane]      * (double)W[lane]
               + (double)x[lane + 64] * (double)W[lane + 64];
    #pragma unroll
    for (int off = 32; off > 0; off >>= 1) acc += __shfl_down(acc, off);
    if (lane == 0) {
        float z32 = (float)acc;
        float u   = (z32 + bias[0]) / 100.0f;
        float e   = (float)exp(-(double)u);
        float t   = 1.0f + e;
        float s   = 1.0f / t;
        scoreF[row] = s;
    }
}

// ---------------- top-400 per (b,class): register bitonic (R3-verified, verbatim) ----------------
__global__ void __launch_bounds__(1024)
topk_kernel(const float* __restrict__ scoreF, int* __restrict__ gidx, float* __restrict__ gvals) {
    __shared__ unsigned long long buf[2][1024];
    const int b = blockIdx.x / NCLS;
    const int c = blockIdx.x % NCLS;
    const int t = threadIdx.x;

    if (c == 0 && t >= 512 && t < 512 + NQ) {
        int q  = t - 512;
        int gi = NSUP + q;
        int m  = NCLS * KK + q;
        gidx [b * MM + m] = gi;
        gvals[b * MM + m] = scoreF[(size_t)b * NN + gi];
    }

    const float* sc = scoreF + (size_t)b * NN + c * SS;
    unsigned long long v = 0ull;    // pad sinks
    if (t < SS)
        v = ((unsigned long long)__float_as_uint(sc[t]) << 32) | (unsigned int)(1023 - t);

    int p = 0;
    for (int k = 2; k <= 1024; k <<= 1) {
        for (int j = k >> 1; j > 0; j >>= 1) {
            unsigned long long o;
            if (j >= 64) {
                buf[p][t] = v;
                __syncthreads();
                o = buf[p][t ^ j];
                p ^= 1;   // next reuse of this buffer is 2 stages (1 barrier) away
            } else {
                unsigned int lo = __shfl_xor((unsigned int)(v & 0xFFFFFFFFu), j);
                unsigned int hi = __shfl_xor((unsigned int)(v >> 32), j);
                o = ((unsigned long long)hi << 32) | lo;
            }
            bool keepMax = (((t & k) == 0) == ((t & j) == 0));
            v = keepMax ? (v > o ? v : o) : (v < o ? v : o);
        }
    }

    if (t < KK) {
        int li = 1023 - (int)(v & 0xFFFFFFFFull);
        gidx [b * MM + c * KK + t] = c * SS + li;
        gvals[b * MM + c * KK + t] = __uint_as_float((unsigned int)(v >> 32));
    }
}

// ---------------- fused new_A + new_X + idx: R10 body, grid-stride persistent ----------------
// Single change vs R10-verified newxa: grid = 2048 blocks (8/CU full residency),
// each block loops over ~4 output rows. Per-row body IDENTICAL to R10 (stage row
// via global_load_lds, newX overlap, barrier, LDS gather with i4 idx from L2).
// Trailing barrier protects rowA before next iteration's staging.
__global__ void __launch_bounds__(256, 8)
newxa_kernel(const float* __restrict__ A, const float* __restrict__ X,
             const int* __restrict__ gidx, const float* __restrict__ gvals,
             float* __restrict__ outA, float* __restrict__ outX, float* __restrict__ outIdx) {
    __shared__ float rowA[NN];
    const int wv = threadIdx.x >> 6, ln = threadIdx.x & 63;

    for (int bm = blockIdx.x; bm < BB * MM; bm += gridDim.x) {
        const int b  = bm / MM;
        const int ri = gidx[bm];              // broadcast scalar load (L2-hot)

        // async stage of the 16KB A row (4 global_load_lds_dwordx4 / wave)
        {
            const float* arow = A + ((size_t)b * NN + ri) * NN;
            #pragma unroll
            for (int sgm = 0; sgm < 4; ++sgm) {
                int base = (wv * 4 + sgm) * 256;               // float offset, wave-uniform
                const float* gsrc = arow + base + ln * 4;      // per-lane global addr
                float*       ldst = rowA + base;               // wave-uniform LDS base
                __builtin_amdgcn_global_load_lds(
                    (__attribute__((address_space(1))) void*)(const_cast<float*>(gsrc)),
                    (__attribute__((address_space(3))) void*)(ldst),
                    16, 0, 0);
            }
        }

        // newX + idx overlap the staging latency
        if (threadIdx.x < DD) {
            float vscale = gvals[bm];
            outX[(size_t)bm * DD + threadIdx.x] =
                X[((size_t)b * NN + ri) * DD + threadIdx.x] * vscale;
            if (threadIdx.x == 0) outIdx[bm] = (float)ri;
        }
        __syncthreads();   // drains vmcnt (global_load_lds)

        // gather: indices via int4 from L2, values from LDS, coalesced f4 stores
        const int* gb = gidx + b * MM;        // 16B-aligned
        float* orow = outA + (size_t)bm * MM;
        for (int jj = threadIdx.x * 4; jj < MM; jj += 1024) {
            i4 c4 = *(const i4*)(gb + jj);
            f4 vv;
            vv.x = rowA[c4.x];
            vv.y = rowA[c4.y];
            vv.z = rowA[c4.z];
            vv.w = rowA[c4.w];
            *(f4*)(orow + jj) = vv;
        }
        __syncthreads();   // rowA reuse guard before next iteration's staging
    }
}

extern "C" void kernel_launch(void* const* d_in, const int* in_sizes, int n_in,
                              void* d_out, int out_size, void* d_ws, size_t ws_size,
                              hipStream_t stream) {
    const float* A  = (const float*)d_in[0];
    const float* X  = (const float*)d_in[1];
    const float* W  = (const float*)d_in[2];
    const float* bi = (const float*)d_in[3];

    float* outA   = (float*)d_out;                         // B*M*M
    float* outX   = outA + (size_t)BB * MM * MM;           // B*M*D
    float* outIdx = outX + (size_t)BB * MM * DD;           // B*M

    char* ws = (char*)d_ws;
    float* scoreF = (float*)ws;                                 // B*N*4 = 65536
    int*   gidx   = (int*)  (ws + 65536);                       // B*M*4 = 33536
    float* gvals  = (float*)(ws + 65536 + 33536);               // B*M*4 = 33536

    score_kernel<<<(BB * NN) / 4, 256, 0, stream>>>(X, W, bi, scoreF);
    topk_kernel<<<BB * NCLS, 1024, 0, stream>>>(scoreF, gidx, gvals);
    newxa_kernel<<<2048, 256, 0, stream>>>(A, X, gidx, gvals, outA, outX, outIdx);
}

// Round 13
// 52.529 us; speedup vs baseline: 1.0707x; 1.0297x over previous
//
#include <hip/hip_runtime.h>
#include <math.h>

#define BB   4
#define NN   4096
#define DD   128
#define NCLS 5
#define SS   800      // (N - NQ) / NCLS
#define KK   400      // int(0.5 * S)
#define NQ   96
#define MM   (NCLS*KK + NQ)   // 2096
#define NSUP (NCLS*SS)        // 4000

typedef float f4 __attribute__((ext_vector_type(4)));
typedef int   i4 __attribute__((ext_vector_type(4)));

// ---------------- scores: f64 dot, exact f32 sigmoid (R2/R3-verified, verbatim) ----------------
__global__ void score_kernel(const float* __restrict__ X, const float* __restrict__ W,
                             const float* __restrict__ bias,
                             float* __restrict__ scoreF) {
    int row  = blockIdx.x * 4 + (threadIdx.x >> 6);   // 4 waves / block
    int lane = threadIdx.x & 63;
    if (row >= BB * NN) return;
    const float* x = X + (size_t)row * DD;
    double acc = (double)x[lane]      * (double)W[lane]
               + (double)x[lane + 64] * (double)W[lane + 64];
    #pragma unroll
    for (int off = 32; off > 0; off >>= 1) acc += __shfl_down(acc, off);
    if (lane == 0) {
        float z32 = (float)acc;
        float u   = (z32 + bias[0]) / 100.0f;
        float e   = (float)exp(-(double)u);
        float t   = 1.0f + e;
        float s   = 1.0f / t;
        scoreF[row] = s;
    }
}

// ---------------- top-400 per (b,class): register bitonic (R3-verified, verbatim) ----------------
__global__ void __launch_bounds__(1024)
topk_kernel(const float* __restrict__ scoreF, int* __restrict__ gidx, float* __restrict__ gvals) {
    __shared__ unsigned long long buf[2][1024];
    const int b = blockIdx.x / NCLS;
    const int c = blockIdx.x % NCLS;
    const int t = threadIdx.x;

    if (c == 0 && t >= 512 && t < 512 + NQ) {
        int q  = t - 512;
        int gi = NSUP + q;
        int m  = NCLS * KK + q;
        gidx [b * MM + m] = gi;
        gvals[b * MM + m] = scoreF[(size_t)b * NN + gi];
    }

    const float* sc = scoreF + (size_t)b * NN + c * SS;
    unsigned long long v = 0ull;    // pad sinks
    if (t < SS)
        v = ((unsigned long long)__float_as_uint(sc[t]) << 32) | (unsigned int)(1023 - t);

    int p = 0;
    for (int k = 2; k <= 1024; k <<= 1) {
        for (int j = k >> 1; j > 0; j >>= 1) {
            unsigned long long o;
            if (j >= 64) {
                buf[p][t] = v;
                __syncthreads();
                o = buf[p][t ^ j];
                p ^= 1;   // next reuse of this buffer is 2 stages (1 barrier) away
            } else {
                unsigned int lo = __shfl_xor((unsigned int)(v & 0xFFFFFFFFu), j);
                unsigned int hi = __shfl_xor((unsigned int)(v >> 32), j);
                o = ((unsigned long long)hi << 32) | lo;
            }
            bool keepMax = (((t & k) == 0) == ((t & j) == 0));
            v = keepMax ? (v > o ? v : o) : (v < o ? v : o);
        }
    }

    if (t < KK) {
        int li = 1023 - (int)(v & 0xFFFFFFFFull);
        gidx [b * MM + c * KK + t] = c * SS + li;
        gvals[b * MM + c * KK + t] = __uint_as_float((unsigned int)(v >> 32));
    }
}

// ---------------- fused new_A + new_X + idx: persistent grid + nt stores ----------------
// Single change vs R12-verified newxa: outA/outX stores are nontemporal (write-once
// data; keep 74MB of dead lines out of L2, reduce eviction pressure on the read
// stream and L2-hot gidx). Everything else identical.
__global__ void __launch_bounds__(256, 8)
newxa_kernel(const float* __restrict__ A, const float* __restrict__ X,
             const int* __restrict__ gidx, const float* __restrict__ gvals,
             float* __restrict__ outA, float* __restrict__ outX, float* __restrict__ outIdx) {
    __shared__ float rowA[NN];
    const int wv = threadIdx.x >> 6, ln = threadIdx.x & 63;

    for (int bm = blockIdx.x; bm < BB * MM; bm += gridDim.x) {
        const int b  = bm / MM;
        const int ri = gidx[bm];              // broadcast scalar load (L2-hot)

        // async stage of the 16KB A row (4 global_load_lds_dwordx4 / wave)
        {
            const float* arow = A + ((size_t)b * NN + ri) * NN;
            #pragma unroll
            for (int sgm = 0; sgm < 4; ++sgm) {
                int base = (wv * 4 + sgm) * 256;               // float offset, wave-uniform
                const float* gsrc = arow + base + ln * 4;      // per-lane global addr
                float*       ldst = rowA + base;               // wave-uniform LDS base
                __builtin_amdgcn_global_load_lds(
                    (__attribute__((address_space(1))) void*)(const_cast<float*>(gsrc)),
                    (__attribute__((address_space(3))) void*)(ldst),
                    16, 0, 0);
            }
        }

        // newX + idx overlap the staging latency
        if (threadIdx.x < DD) {
            float vscale = gvals[bm];
            float xv = X[((size_t)b * NN + ri) * DD + threadIdx.x] * vscale;
            __builtin_nontemporal_store(xv, outX + (size_t)bm * DD + threadIdx.x);
            if (threadIdx.x == 0) outIdx[bm] = (float)ri;
        }
        __syncthreads();   // drains vmcnt (global_load_lds)

        // gather: indices via int4 from L2, values from LDS, nt f4 stores
        const int* gb = gidx + b * MM;        // 16B-aligned
        float* orow = outA + (size_t)bm * MM;
        for (int jj = threadIdx.x * 4; jj < MM; jj += 1024) {
            i4 c4 = *(const i4*)(gb + jj);
            f4 vv;
            vv.x = rowA[c4.x];
            vv.y = rowA[c4.y];
            vv.z = rowA[c4.z];
            vv.w = rowA[c4.w];
            __builtin_nontemporal_store(vv, (f4*)(orow + jj));
        }
        __syncthreads();   // rowA reuse guard before next iteration's staging
    }
}

extern "C" void kernel_launch(void* const* d_in, const int* in_sizes, int n_in,
                              void* d_out, int out_size, void* d_ws, size_t ws_size,
                              hipStream_t stream) {
    const float* A  = (const float*)d_in[0];
    const float* X  = (const float*)d_in[1];
    const float* W  = (const float*)d_in[2];
    const float* bi = (const float*)d_in[3];

    float* outA   = (float*)d_out;                         // B*M*M
    float* outX   = outA + (size_t)BB * MM * MM;           // B*M*D
    float* outIdx = outX + (size_t)BB * MM * DD;           // B*M

    char* ws = (char*)d_ws;
    float* scoreF = (float*)ws;                                 // B*N*4 = 65536
    int*   gidx   = (int*)  (ws + 65536);                       // B*M*4 = 33536
    float* gvals  = (float*)(ws + 65536 + 33536);               // B*M*4 = 33536

    score_kernel<<<(BB * NN) / 4, 256, 0, stream>>>(X, W, bi, scoreF);
    topk_kernel<<<BB * NCLS, 1024, 0, stream>>>(scoreF, gidx, gvals);
    newxa_kernel<<<2048, 256, 0, stream>>>(A, X, gidx, gvals, outA, outX, outIdx);
}